// Round 10
// baseline (207.848 us; speedup 1.0000x reference)
//
#include <hip/hip_runtime.h>

#define D_MODEL 1024
#define SEQ     2048
#define BATCH   2
#define NHEAD   16
#define HDIM    64

typedef __attribute__((ext_vector_type(4))) float  f32x4;
typedef __attribute__((ext_vector_type(8))) __bf16 bf16x8;
typedef __attribute__((ext_vector_type(4))) __bf16 bf16x4;
typedef __attribute__((ext_vector_type(2))) unsigned int u32x2;

__device__ __forceinline__ void gld_lds16(const void* g, void* l) {
  __builtin_amdgcn_global_load_lds(
      (const __attribute__((address_space(1))) void*)g,
      (__attribute__((address_space(3))) void*)l, 16, 0, 0);
}

// ---------------- convert x (fp32 -> bf16), vectorized ----------------
__global__ void k_convert(const float* __restrict__ in, __bf16* __restrict__ out) {
  int i = blockIdx.x * blockDim.x + threadIdx.x;   // one float4 per thread
  float4 v = ((const float4*)in)[i];
  bf16x4 o;
  o[0] = (__bf16)v.x; o[1] = (__bf16)v.y; o[2] = (__bf16)v.z; o[3] = (__bf16)v.w;
  ((bf16x4*)out)[i] = o;
}

// ------------- transpose + convert weights: W[k][n] -> Wt[n][k] bf16 -------------
// Wq is additionally scaled by 1/sqrt(D_MODEL) = 1/32 (exact in bf16).
__global__ void k_transw(const float* __restrict__ Wq, const float* __restrict__ Wk,
                         const float* __restrict__ Wv, const float* __restrict__ Wo,
                         __bf16* __restrict__ Wqkvt, __bf16* __restrict__ Wot) {
  __shared__ __bf16 T[64][72];
  const int z = blockIdx.z;
  const float* src = (z==0)?Wq:(z==1)?Wk:(z==2)?Wv:Wo;
  __bf16* dst = (z<3) ? (Wqkvt + (size_t)z*D_MODEL*D_MODEL) : Wot;
  const float scl = (z==0) ? 0.03125f : 1.0f;      // fold softmax scale into Wq
  const int k0 = blockIdx.x*64, n0 = blockIdx.y*64;
  const int t = threadIdx.x;
  const int kl = t>>4, nl4 = (t&15)*4;
  #pragma unroll
  for (int part = 0; part < 4; ++part) {
    const int k = part*16 + kl;
    float4 v = *(const float4*)(src + (size_t)(k0+k)*D_MODEL + n0 + nl4);
    T[nl4+0][k] = (__bf16)(v.x*scl);
    T[nl4+1][k] = (__bf16)(v.y*scl);
    T[nl4+2][k] = (__bf16)(v.z*scl);
    T[nl4+3][k] = (__bf16)(v.w*scl);
  }
  __syncthreads();
  const int nl = t>>3, kc = (t&7)*8;
  #pragma unroll
  for (int part = 0; part < 2; ++part) {
    int n = part*32 + nl;
    bf16x8 o = *(const bf16x8*)&T[n][kc];
    *(bf16x8*)(dst + (size_t)(n0+n)*D_MODEL + k0 + kc) = o;
  }
}

// ------------- bf16 MFMA GEMM, 128 x (32*NI) tile, BK=32, Bt is [N][K] -------------
// NI = B-fragments per wave (4 -> BN=128, 2 -> BN=64).
// BN=64 exists for the out-proj: 128x128 gave 256 blocks = 1 block/CU (zero
// cross-block overlap on the vmcnt(0)+barrier drain); 128x64 -> 512 = 2/CU.
template<int OUTF32, int NI>
__global__ __launch_bounds__(256)
void k_gemm_bt(const __bf16* __restrict__ A, const __bf16* __restrict__ Bt,
               void* __restrict__ Cv, const float* __restrict__ bias,
               const int K, const int N) {
  __shared__ __bf16 As[128*32];
  __shared__ __bf16 Bs[NI*32*32];        // BN = NI*32 rows x 32 k
  const int t = threadIdx.x;
  const int w = t>>6, l = t&63;
  const int lr = l&15, g = l>>4;
  const int BN = NI*32;
  const int m0 = blockIdx.y*128, n0 = blockIdx.x*BN;
  const int wr = (w>>1)*64, wc = (w&1)*(16*NI);
  f32x4 acc[4][NI] = {};

  const int srow = w*16 + (l>>2);
  const int sc8  = (l&3)*8;
  const __bf16* Ag = A  + (size_t)(m0 + srow)*K + sc8;
  const __bf16* Bg = Bt + (size_t)(n0 + srow)*K + sc8;
  char* Al = (char*)As + w*1024;
  char* Bl = (char*)Bs + w*1024;

  for (int k0 = 0; k0 < K; k0 += 32) {
    __syncthreads();
    gld_lds16(Ag + k0,                 Al);
    gld_lds16(Ag + (size_t)64*K + k0,  Al + 4096);
    gld_lds16(Bg + k0,                 Bl);
    if (NI == 4)
      gld_lds16(Bg + (size_t)64*K + k0, Bl + 4096);
    __syncthreads();
    bf16x8 af[4], bf[NI];
    #pragma unroll
    for (int mi=0;mi<4;++mi)
      af[mi] = *(const bf16x8*)((const char*)As + (wr + mi*16 + lr)*64 + (g<<4));
    #pragma unroll
    for (int ni=0;ni<NI;++ni)
      bf[ni] = *(const bf16x8*)((const char*)Bs + (wc + ni*16 + lr)*64 + (g<<4));
    #pragma unroll
    for (int mi=0;mi<4;++mi)
      #pragma unroll
      for (int ni=0;ni<NI;++ni)
        acc[mi][ni] = __builtin_amdgcn_mfma_f32_16x16x32_bf16(af[mi], bf[ni], acc[mi][ni], 0, 0, 0);
  }

  if (OUTF32) {
    float* C = (float*)Cv;
    #pragma unroll
    for (int ni=0;ni<NI;++ni) {
      const int col = n0 + wc + ni*16 + lr;
      const float bv = bias[col];
      #pragma unroll
      for (int mi=0;mi<4;++mi)
        #pragma unroll
        for (int r=0;r<4;++r) {
          const int row = m0 + wr + mi*16 + g*4 + r;
          C[(size_t)row*N + col] = acc[mi][ni][r] + bv;
        }
    }
  } else {
    __bf16* C = (__bf16*)Cv;
    #pragma unroll
    for (int ni=0;ni<NI;++ni) {
      const int col = n0 + wc + ni*16 + lr;
      #pragma unroll
      for (int mi=0;mi<4;++mi)
        #pragma unroll
        for (int r=0;r<4;++r) {
          const int row = m0 + wr + mi*16 + g*4 + r;
          C[(size_t)row*N + col] = (__bf16)acc[mi][ni][r];
        }
    }
  }
}

// ------------- causal flash attention, swapped-QK^T structure -------------
// One q-tile (64 rows) per block; grid = 1024 linear.
// XCD swizzle: all 32 q-blocks of one (b,h) share id%8 -> same XCD L2 holds
// that head's K/V (512 KB; 4 heads/XCD = 2 MB < 4 MB L2).
// Dispatch order: qb descending -> big blocks start first (makespan).
// Defer-max (T13, THR=8): skip rescale when tile max hasn't grown past m+8.
__global__ __launch_bounds__(256)
void k_attn(const __bf16* __restrict__ QKV, __bf16* __restrict__ AO) {
  __shared__ __bf16 Ks[2][64*64];   // [key][dh] rows 128B, chunk ^= (key&7)
  __shared__ __bf16 Vs[2][64*64];   // subtiled [kb][nb][16][16] row-major, 512B each
  const int t = threadIdx.x;
  const int w = t>>6, l = t&63;
  const int lr = l&15, g = l>>4;

  const int id = blockIdx.x;
  const int xcd = id & 7, j = id >> 3;
  const int qb = 31 - (j & 31);              // descending: big tiles dispatch first
  const int bh = xcd + 8*(j >> 5);           // 32 q-blocks of a bh share the XCD
  const int b = bh >> 4, h = bh & 15;
  const size_t rb = (size_t)b*SEQ;
  const int nt = qb + 1;
  const int q0 = qb*64 + w*16;

  // staging: thread -> (key row skey / skey+32, dh chunk sc*8)
  const int skey = t>>3, sc = t&7;
  const __bf16* Kg = QKV + rb*3072 + 1024 + h*64 + sc*8;
  const __bf16* Vg = Kg + 1024;
  const int ksw = skey*128 + ((sc ^ (skey&7))<<4);                        // K write byte off
  const int vsw = ((skey>>4)*4 + (sc>>1))*512 + (skey&15)*32 + (sc&1)*16; // V write byte off

  // Q fragments (B-operand: col q = q0+lr, k-slice dh = kc*32+g*8)
  bf16x8 qf[2];
  #pragma unroll
  for (int kc=0;kc<2;++kc)
    qf[kc] = *(const bf16x8*)(QKV + (rb + q0 + lr)*3072 + h*64 + kc*32 + g*8);

  f32x4 oacc[4] = {};
  float mrun = -1e30f, lrun = 0.f;

  // prologue: tile 0 -> regs -> LDS buf0; then prefetch tile 1 -> regs
  uint4 kR0 = *(const uint4*)(Kg + (size_t)skey*3072);
  uint4 kR1 = *(const uint4*)(Kg + (size_t)(skey+32)*3072);
  uint4 vR0 = *(const uint4*)(Vg + (size_t)skey*3072);
  uint4 vR1 = *(const uint4*)(Vg + (size_t)(skey+32)*3072);
  {
    char* K0 = (char*)&Ks[0][0]; char* V0 = (char*)&Vs[0][0];
    *(uint4*)(K0 + ksw) = kR0;  *(uint4*)(K0 + ksw + 4096) = kR1;
    *(uint4*)(V0 + vsw) = vR0;  *(uint4*)(V0 + vsw + 4096) = vR1;
  }
  if (nt > 1) {
    kR0 = *(const uint4*)(Kg + (size_t)(64+skey)*3072);
    kR1 = *(const uint4*)(Kg + (size_t)(64+skey+32)*3072);
    vR0 = *(const uint4*)(Vg + (size_t)(64+skey)*3072);
    vR1 = *(const uint4*)(Vg + (size_t)(64+skey+32)*3072);
  }

  int cur = 0;
  for (int kt = 0; kt < nt; ++kt) {
    __syncthreads();                     // buf[cur] fully written; prev reads done
    if (kt+1 < nt) {                     // stage next tile into other buffer
      char* Kn = (char*)&Ks[cur^1][0]; char* Vn = (char*)&Vs[cur^1][0];
      *(uint4*)(Kn + ksw) = kR0;  *(uint4*)(Kn + ksw + 4096) = kR1;
      *(uint4*)(Vn + vsw) = vR0;  *(uint4*)(Vn + vsw + 4096) = vR1;
      if (kt+2 < nt) {                   // issue loads for tile kt+2 (hide under compute)
        const size_t base = (size_t)(kt+2)*64;
        kR0 = *(const uint4*)(Kg + (base+skey)*3072);
        kR1 = *(const uint4*)(Kg + (base+skey+32)*3072);
        vR0 = *(const uint4*)(Vg + (base+skey)*3072);
        vR1 = *(const uint4*)(Vg + (base+skey+32)*3072);
      }
    }

    // ---- QK^T (swapped: A=K rows, B=Q cols) ----
    const char* Kb = (const char*)&Ks[cur][0];
    f32x4 sa[4] = {};
    #pragma unroll
    for (int kc=0;kc<2;++kc)
      #pragma unroll
      for (int kb=0;kb<4;++kb) {
        bf16x8 kfv = *(const bf16x8*)(Kb + (kb*16+lr)*128 + (((kc*4+g) ^ (lr&7))<<4));
        sa[kb] = __builtin_amdgcn_mfma_f32_16x16x32_bf16(kfv, qf[kc], sa[kb], 0,0,0);
      }

    if (kt == nt-1) {                    // diagonal tile: causal mask
      const int qg = q0 + lr;
      #pragma unroll
      for (int kb=0;kb<4;++kb)
        #pragma unroll
        for (int r=0;r<4;++r)
          if (kt*64 + kb*16 + 4*g + r > qg) sa[kb][r] = -1e30f;
    }

    // ---- online softmax (lane-local row q=q0+lr; reduce over 4 g-lanes) ----
    float mx = sa[0][0];
    #pragma unroll
    for (int kb=0;kb<4;++kb)
      #pragma unroll
      for (int r=0;r<4;++r) mx = fmaxf(mx, sa[kb][r]);
    mx = fmaxf(mx, __shfl_xor(mx, 16));
    mx = fmaxf(mx, __shfl_xor(mx, 32));
    if (!__all(mx <= mrun + 8.0f)) {     // defer-max: rescale only on real growth
      const float mnew = fmaxf(mrun, mx);
      const float al = __expf(mrun - mnew);
      lrun *= al;
      float alq[4];
      #pragma unroll
      for (int r=0;r<4;++r) alq[r] = __shfl(al, g*4+r);
      #pragma unroll
      for (int nb=0;nb<4;++nb)
        #pragma unroll
        for (int r=0;r<4;++r) oacc[nb][r] *= alq[r];
      mrun = mnew;
    }
    float ls = 0.f;
    #pragma unroll
    for (int kb=0;kb<4;++kb)
      #pragma unroll
      for (int r=0;r<4;++r) { float p = __expf(sa[kb][r]-mrun); sa[kb][r] = p; ls += p; }
    ls += __shfl_xor(ls, 16);
    ls += __shfl_xor(ls, 32);
    lrun += ls;

    // ---- PV: pa lane-local pack; V via hw transpose read ----
    // Key-permutation note (verified R5): pa slot (g, j / 4+j) holds keys
    // 32kc+4g+j / 32kc+16+4g+j; tr_read of subtiles [2kc][nb],[2kc+1][nb]
    // delivers V for the SAME per-slot keys -> contraction exact.
    const __attribute__((address_space(3))) char* trp =
        (const __attribute__((address_space(3))) char*)((const char*)&Vs[cur][0]) + l*8;
    #pragma unroll
    for (int kc=0;kc<2;++kc) {
      bf16x8 pa;
      #pragma unroll
      for (int j2=0;j2<4;++j2) { pa[j2] = (__bf16)sa[2*kc][j2]; pa[4+j2] = (__bf16)sa[2*kc+1][j2]; }
      u32x2 t0[4], t1[4];
      #pragma unroll
      for (int nb=0;nb<4;++nb) {
        asm volatile("ds_read_b64_tr_b16 %0, %1 offset:%2"
                     : "=v"(t0[nb]) : "v"(trp), "i"(((2*kc)*4+nb)*512) : "memory");
        asm volatile("ds_read_b64_tr_b16 %0, %1 offset:%2"
                     : "=v"(t1[nb]) : "v"(trp), "i"(((2*kc+1)*4+nb)*512) : "memory");
      }
      asm volatile("s_waitcnt lgkmcnt(0)" ::: "memory");
      __builtin_amdgcn_sched_barrier(0);   // rule 18: don't hoist MFMA above the wait
      #pragma unroll
      for (int nb=0;nb<4;++nb) {
        union { u32x2 h[2]; bf16x8 v; } U;
        U.h[0] = t0[nb]; U.h[1] = t1[nb];
        oacc[nb] = __builtin_amdgcn_mfma_f32_16x16x32_bf16(pa, U.v, oacc[nb], 0,0,0);
      }
    }
    cur ^= 1;
  }

  // ---- epilogue: divide by l, write AO ----
  const float rinv = 1.0f / lrun;
  float rq[4];
  #pragma unroll
  for (int r=0;r<4;++r) rq[r] = __shfl(rinv, g*4+r);
  #pragma unroll
  for (int nb=0;nb<4;++nb)
    #pragma unroll
    for (int r=0;r<4;++r)
      AO[(rb + q0 + g*4 + r)*1024 + h*64 + nb*16 + lr] = (__bf16)(oacc[nb][r] * rq[r]);
}

extern "C" void kernel_launch(void* const* d_in, const int* in_sizes, int n_in,
                              void* d_out, int out_size, void* d_ws, size_t ws_size,
                              hipStream_t stream) {
  (void)in_sizes; (void)n_in; (void)out_size; (void)ws_size;
  const float* x  = (const float*)d_in[0];
  const float* Wq = (const float*)d_in[1];
  const float* Wk = (const float*)d_in[2];
  const float* Wv = (const float*)d_in[3];
  const float* Wo = (const float*)d_in[4];
  const float* bo = (const float*)d_in[5];
  float* out = (float*)d_out;
  char* ws = (char*)d_ws;

  __bf16* Xbf   = (__bf16*)(ws);                      // [0,8M)   x bf16; reused as AO
  __bf16* Wqkvt = (__bf16*)(ws + (size_t)(8<<20));    // [8M,14M) Wq|Wk|Wv ^T [3072][1024]
  __bf16* Wot   = (__bf16*)(ws + (size_t)(14<<20));   // [14M,16M) Wo ^T [1024][1024]
  __bf16* QKV   = (__bf16*)(ws + (size_t)(16<<20));   // [16M,40M) [4096][3072]
  __bf16* AO    = Xbf;

  k_convert<<<4096, 256, 0, stream>>>(x, Xbf);
  k_transw<<<dim3(16,16,4), 256, 0, stream>>>(Wq, Wk, Wv, Wo, Wqkvt, Wot);
  k_gemm_bt<0,4><<<dim3(24,32), 256, 0, stream>>>(Xbf, Wqkvt, (void*)QKV, nullptr, 1024, 3072);
  k_attn<<<1024, 256, 0, stream>>>(QKV, AO);
  k_gemm_bt<1,2><<<dim3(16,32), 256, 0, stream>>>(AO, Wot, (void*)out, bo, 1024, 1024);
}

// Round 11
// 190.676 us; speedup vs baseline: 1.0901x; 1.0901x over previous
//
#include <hip/hip_runtime.h>

#define D_MODEL 1024
#define SEQ     2048
#define BATCH   2
#define NHEAD   16
#define HDIM    64

typedef __attribute__((ext_vector_type(4))) float  f32x4;
typedef __attribute__((ext_vector_type(8))) __bf16 bf16x8;
typedef __attribute__((ext_vector_type(4))) __bf16 bf16x4;
typedef __attribute__((ext_vector_type(2))) unsigned int u32x2;

__device__ __forceinline__ void gld_lds16(const void* g, void* l) {
  __builtin_amdgcn_global_load_lds(
      (const __attribute__((address_space(1))) void*)g,
      (__attribute__((address_space(3))) void*)l, 16, 0, 0);
}

// ---------------- convert x (fp32 -> bf16), vectorized ----------------
__global__ void k_convert(const float* __restrict__ in, __bf16* __restrict__ out) {
  int i = blockIdx.x * blockDim.x + threadIdx.x;   // one float4 per thread
  float4 v = ((const float4*)in)[i];
  bf16x4 o;
  o[0] = (__bf16)v.x; o[1] = (__bf16)v.y; o[2] = (__bf16)v.z; o[3] = (__bf16)v.w;
  ((bf16x4*)out)[i] = o;
}

// ------------- transpose + convert weights: W[k][n] -> Wt[n][k] bf16 -------------
// Wq is additionally scaled by 1/sqrt(D_MODEL) = 1/32 (exact in bf16).
__global__ void k_transw(const float* __restrict__ Wq, const float* __restrict__ Wk,
                         const float* __restrict__ Wv, const float* __restrict__ Wo,
                         __bf16* __restrict__ Wqkvt, __bf16* __restrict__ Wot) {
  __shared__ __bf16 T[64][72];
  const int z = blockIdx.z;
  const float* src = (z==0)?Wq:(z==1)?Wk:(z==2)?Wv:Wo;
  __bf16* dst = (z<3) ? (Wqkvt + (size_t)z*D_MODEL*D_MODEL) : Wot;
  const float scl = (z==0) ? 0.03125f : 1.0f;      // fold softmax scale into Wq
  const int k0 = blockIdx.x*64, n0 = blockIdx.y*64;
  const int t = threadIdx.x;
  const int kl = t>>4, nl4 = (t&15)*4;
  #pragma unroll
  for (int part = 0; part < 4; ++part) {
    const int k = part*16 + kl;
    float4 v = *(const float4*)(src + (size_t)(k0+k)*D_MODEL + n0 + nl4);
    T[nl4+0][k] = (__bf16)(v.x*scl);
    T[nl4+1][k] = (__bf16)(v.y*scl);
    T[nl4+2][k] = (__bf16)(v.z*scl);
    T[nl4+3][k] = (__bf16)(v.w*scl);
  }
  __syncthreads();
  const int nl = t>>3, kc = (t&7)*8;
  #pragma unroll
  for (int part = 0; part < 2; ++part) {
    int n = part*32 + nl;
    bf16x8 o = *(const bf16x8*)&T[n][kc];
    *(bf16x8*)(dst + (size_t)(n0+n)*D_MODEL + k0 + kc) = o;
  }
}

// ------------- bf16 MFMA GEMM, 128 x (32*NI) tile, BK=32, Bt is [N][K] -------------
// NI = B-fragments per wave (4 -> BN=128, 2 -> BN=64).
template<int OUTF32, int NI>
__global__ __launch_bounds__(256)
void k_gemm_bt(const __bf16* __restrict__ A, const __bf16* __restrict__ Bt,
               void* __restrict__ Cv, const float* __restrict__ bias,
               const int K, const int N) {
  __shared__ __bf16 As[128*32];
  __shared__ __bf16 Bs[NI*32*32];        // BN = NI*32 rows x 32 k
  const int t = threadIdx.x;
  const int w = t>>6, l = t&63;
  const int lr = l&15, g = l>>4;
  const int BN = NI*32;
  const int m0 = blockIdx.y*128, n0 = blockIdx.x*BN;
  const int wr = (w>>1)*64, wc = (w&1)*(16*NI);
  f32x4 acc[4][NI] = {};

  const int srow = w*16 + (l>>2);
  const int sc8  = (l&3)*8;
  const __bf16* Ag = A  + (size_t)(m0 + srow)*K + sc8;
  const __bf16* Bg = Bt + (size_t)(n0 + srow)*K + sc8;
  char* Al = (char*)As + w*1024;
  char* Bl = (char*)Bs + w*1024;

  for (int k0 = 0; k0 < K; k0 += 32) {
    __syncthreads();
    gld_lds16(Ag + k0,                 Al);
    gld_lds16(Ag + (size_t)64*K + k0,  Al + 4096);
    gld_lds16(Bg + k0,                 Bl);
    if (NI == 4)
      gld_lds16(Bg + (size_t)64*K + k0, Bl + 4096);
    __syncthreads();
    bf16x8 af[4], bf[NI];
    #pragma unroll
    for (int mi=0;mi<4;++mi)
      af[mi] = *(const bf16x8*)((const char*)As + (wr + mi*16 + lr)*64 + (g<<4));
    #pragma unroll
    for (int ni=0;ni<NI;++ni)
      bf[ni] = *(const bf16x8*)((const char*)Bs + (wc + ni*16 + lr)*64 + (g<<4));
    #pragma unroll
    for (int mi=0;mi<4;++mi)
      #pragma unroll
      for (int ni=0;ni<NI;++ni)
        acc[mi][ni] = __builtin_amdgcn_mfma_f32_16x16x32_bf16(af[mi], bf[ni], acc[mi][ni], 0, 0, 0);
  }

  if (OUTF32) {
    float* C = (float*)Cv;
    #pragma unroll
    for (int ni=0;ni<NI;++ni) {
      const int col = n0 + wc + ni*16 + lr;
      const float bv = bias[col];
      #pragma unroll
      for (int mi=0;mi<4;++mi)
        #pragma unroll
        for (int r=0;r<4;++r) {
          const int row = m0 + wr + mi*16 + g*4 + r;
          C[(size_t)row*N + col] = acc[mi][ni][r] + bv;
        }
    }
  } else {
    __bf16* C = (__bf16*)Cv;
    #pragma unroll
    for (int ni=0;ni<NI;++ni) {
      const int col = n0 + wc + ni*16 + lr;
      #pragma unroll
      for (int mi=0;mi<4;++mi)
        #pragma unroll
        for (int r=0;r<4;++r) {
          const int row = m0 + wr + mi*16 + g*4 + r;
          C[(size_t)row*N + col] = (__bf16)acc[mi][ni][r];
        }
    }
  }
}

// ------------- causal flash attention, swapped-QK^T structure -------------
// One q-tile (64 rows) per block; grid = 1024 (all co-resident, 4 blocks/CU).
// MAKESPAN FIX (R10 counters): dispatch gives CU c blocks {c, c+256, c+512,
// c+768} (measured: old qb=f(id mod 256) put FOUR EQUAL-qb blocks per CU ->
// worst CU did 128 iters, 70us). New map: sweep s = (id>>3)>>5 alternates
// qb = cc / 31-cc  ->  per-CU iters = (cc+1)+(32-cc)+(cc+1)+(32-cc) = 66,
// uniform for every CU. bh = xcd + 8s keeps each bh's K/V on one XCD's L2
// (measured win: FETCH 119MB -> 12MB).
__global__ __launch_bounds__(256)
void k_attn(const __bf16* __restrict__ QKV, __bf16* __restrict__ AO) {
  __shared__ __bf16 Ks[2][64*64];   // [key][dh] rows 128B, chunk ^= (key&7)
  __shared__ __bf16 Vs[2][64*64];   // subtiled [kb][nb][16][16] row-major, 512B each
  const int t = threadIdx.x;
  const int w = t>>6, l = t&63;
  const int lr = l&15, g = l>>4;

  const int id = blockIdx.x;
  const int xcd = id & 7, j = id >> 3;
  const int s = j >> 5, cc = j & 31;
  const int qb = (s & 1) ? (31 - cc) : cc;   // complementary sizes per CU
  const int bh = xcd + 8*s;                  // all 32 q-blocks of bh on XCD xcd
  const int b = bh >> 4, h = bh & 15;
  const size_t rb = (size_t)b*SEQ;
  const int nt = qb + 1;
  const int q0 = qb*64 + w*16;

  // staging: thread -> (key row skey / skey+32, dh chunk sc*8)
  const int skey = t>>3, sc = t&7;
  const __bf16* Kg = QKV + rb*3072 + 1024 + h*64 + sc*8;
  const __bf16* Vg = Kg + 1024;
  const int ksw = skey*128 + ((sc ^ (skey&7))<<4);                        // K write byte off
  const int vsw = ((skey>>4)*4 + (sc>>1))*512 + (skey&15)*32 + (sc&1)*16; // V write byte off

  // Q fragments (B-operand: col q = q0+lr, k-slice dh = kc*32+g*8)
  bf16x8 qf[2];
  #pragma unroll
  for (int kc=0;kc<2;++kc)
    qf[kc] = *(const bf16x8*)(QKV + (rb + q0 + lr)*3072 + h*64 + kc*32 + g*8);

  f32x4 oacc[4] = {};
  float mrun = -1e30f, lrun = 0.f;

  // prologue: tile 0 -> regs -> LDS buf0; then prefetch tile 1 -> regs
  uint4 kR0 = *(const uint4*)(Kg + (size_t)skey*3072);
  uint4 kR1 = *(const uint4*)(Kg + (size_t)(skey+32)*3072);
  uint4 vR0 = *(const uint4*)(Vg + (size_t)skey*3072);
  uint4 vR1 = *(const uint4*)(Vg + (size_t)(skey+32)*3072);
  {
    char* K0 = (char*)&Ks[0][0]; char* V0 = (char*)&Vs[0][0];
    *(uint4*)(K0 + ksw) = kR0;  *(uint4*)(K0 + ksw + 4096) = kR1;
    *(uint4*)(V0 + vsw) = vR0;  *(uint4*)(V0 + vsw + 4096) = vR1;
  }
  if (nt > 1) {
    kR0 = *(const uint4*)(Kg + (size_t)(64+skey)*3072);
    kR1 = *(const uint4*)(Kg + (size_t)(64+skey+32)*3072);
    vR0 = *(const uint4*)(Vg + (size_t)(64+skey)*3072);
    vR1 = *(const uint4*)(Vg + (size_t)(64+skey+32)*3072);
  }

  int cur = 0;
  for (int kt = 0; kt < nt; ++kt) {
    __syncthreads();                     // buf[cur] fully written; prev reads done
    if (kt+1 < nt) {                     // stage next tile into other buffer
      char* Kn = (char*)&Ks[cur^1][0]; char* Vn = (char*)&Vs[cur^1][0];
      *(uint4*)(Kn + ksw) = kR0;  *(uint4*)(Kn + ksw + 4096) = kR1;
      *(uint4*)(Vn + vsw) = vR0;  *(uint4*)(Vn + vsw + 4096) = vR1;
      if (kt+2 < nt) {                   // issue loads for tile kt+2 (hide under compute)
        const size_t base = (size_t)(kt+2)*64;
        kR0 = *(const uint4*)(Kg + (base+skey)*3072);
        kR1 = *(const uint4*)(Kg + (base+skey+32)*3072);
        vR0 = *(const uint4*)(Vg + (base+skey)*3072);
        vR1 = *(const uint4*)(Vg + (base+skey+32)*3072);
      }
    }

    // ---- QK^T (swapped: A=K rows, B=Q cols) ----
    const char* Kb = (const char*)&Ks[cur][0];
    f32x4 sa[4] = {};
    #pragma unroll
    for (int kc=0;kc<2;++kc)
      #pragma unroll
      for (int kb=0;kb<4;++kb) {
        bf16x8 kfv = *(const bf16x8*)(Kb + (kb*16+lr)*128 + (((kc*4+g) ^ (lr&7))<<4));
        sa[kb] = __builtin_amdgcn_mfma_f32_16x16x32_bf16(kfv, qf[kc], sa[kb], 0,0,0);
      }

    if (kt == nt-1) {                    // diagonal tile: causal mask
      const int qg = q0 + lr;
      #pragma unroll
      for (int kb=0;kb<4;++kb)
        #pragma unroll
        for (int r=0;r<4;++r)
          if (kt*64 + kb*16 + 4*g + r > qg) sa[kb][r] = -1e30f;
    }

    // ---- online softmax (lane-local row q=q0+lr; reduce over 4 g-lanes) ----
    float mx = sa[0][0];
    #pragma unroll
    for (int kb=0;kb<4;++kb)
      #pragma unroll
      for (int r=0;r<4;++r) mx = fmaxf(mx, sa[kb][r]);
    mx = fmaxf(mx, __shfl_xor(mx, 16));
    mx = fmaxf(mx, __shfl_xor(mx, 32));
    if (!__all(mx <= mrun + 8.0f)) {     // defer-max: rescale only on real growth
      const float mnew = fmaxf(mrun, mx);
      const float al = __expf(mrun - mnew);
      lrun *= al;
      float alq[4];
      #pragma unroll
      for (int r=0;r<4;++r) alq[r] = __shfl(al, g*4+r);
      #pragma unroll
      for (int nb=0;nb<4;++nb)
        #pragma unroll
        for (int r=0;r<4;++r) oacc[nb][r] *= alq[r];
      mrun = mnew;
    }
    float ls = 0.f;
    #pragma unroll
    for (int kb=0;kb<4;++kb)
      #pragma unroll
      for (int r=0;r<4;++r) { float p = __expf(sa[kb][r]-mrun); sa[kb][r] = p; ls += p; }
    ls += __shfl_xor(ls, 16);
    ls += __shfl_xor(ls, 32);
    lrun += ls;

    // ---- PV: pa lane-local pack; V via hw transpose read ----
    // Key-permutation note (verified R5): pa slot (g, j / 4+j) holds keys
    // 32kc+4g+j / 32kc+16+4g+j; tr_read of subtiles [2kc][nb],[2kc+1][nb]
    // delivers V for the SAME per-slot keys -> contraction exact.
    const __attribute__((address_space(3))) char* trp =
        (const __attribute__((address_space(3))) char*)((const char*)&Vs[cur][0]) + l*8;
    #pragma unroll
    for (int kc=0;kc<2;++kc) {
      bf16x8 pa;
      #pragma unroll
      for (int j2=0;j2<4;++j2) { pa[j2] = (__bf16)sa[2*kc][j2]; pa[4+j2] = (__bf16)sa[2*kc+1][j2]; }
      u32x2 t0[4], t1[4];
      #pragma unroll
      for (int nb=0;nb<4;++nb) {
        asm volatile("ds_read_b64_tr_b16 %0, %1 offset:%2"
                     : "=v"(t0[nb]) : "v"(trp), "i"(((2*kc)*4+nb)*512) : "memory");
        asm volatile("ds_read_b64_tr_b16 %0, %1 offset:%2"
                     : "=v"(t1[nb]) : "v"(trp), "i"(((2*kc+1)*4+nb)*512) : "memory");
      }
      asm volatile("s_waitcnt lgkmcnt(0)" ::: "memory");
      __builtin_amdgcn_sched_barrier(0);   // rule 18: don't hoist MFMA above the wait
      #pragma unroll
      for (int nb=0;nb<4;++nb) {
        union { u32x2 h[2]; bf16x8 v; } U;
        U.h[0] = t0[nb]; U.h[1] = t1[nb];
        oacc[nb] = __builtin_amdgcn_mfma_f32_16x16x32_bf16(pa, U.v, oacc[nb], 0,0,0);
      }
    }
    cur ^= 1;
  }

  // ---- epilogue: divide by l, write AO ----
  const float rinv = 1.0f / lrun;
  float rq[4];
  #pragma unroll
  for (int r=0;r<4;++r) rq[r] = __shfl(rinv, g*4+r);
  #pragma unroll
  for (int nb=0;nb<4;++nb)
    #pragma unroll
    for (int r=0;r<4;++r)
      AO[(rb + q0 + g*4 + r)*1024 + h*64 + nb*16 + lr] = (__bf16)(oacc[nb][r] * rq[r]);
}

extern "C" void kernel_launch(void* const* d_in, const int* in_sizes, int n_in,
                              void* d_out, int out_size, void* d_ws, size_t ws_size,
                              hipStream_t stream) {
  (void)in_sizes; (void)n_in; (void)out_size; (void)ws_size;
  const float* x  = (const float*)d_in[0];
  const float* Wq = (const float*)d_in[1];
  const float* Wk = (const float*)d_in[2];
  const float* Wv = (const float*)d_in[3];
  const float* Wo = (const float*)d_in[4];
  const float* bo = (const float*)d_in[5];
  float* out = (float*)d_out;
  char* ws = (char*)d_ws;

  __bf16* Xbf   = (__bf16*)(ws);                      // [0,8M)   x bf16; reused as AO
  __bf16* Wqkvt = (__bf16*)(ws + (size_t)(8<<20));    // [8M,14M) Wq|Wk|Wv ^T [3072][1024]
  __bf16* Wot   = (__bf16*)(ws + (size_t)(14<<20));   // [14M,16M) Wo ^T [1024][1024]
  __bf16* QKV   = (__bf16*)(ws + (size_t)(16<<20));   // [16M,40M) [4096][3072]
  __bf16* AO    = Xbf;

  k_convert<<<4096, 256, 0, stream>>>(x, Xbf);
  k_transw<<<dim3(16,16,4), 256, 0, stream>>>(Wq, Wk, Wv, Wo, Wqkvt, Wot);
  k_gemm_bt<0,4><<<dim3(24,32), 256, 0, stream>>>(Xbf, Wqkvt, (void*)QKV, nullptr, 1024, 3072);
  k_attn<<<1024, 256, 0, stream>>>(QKV, AO);
  k_gemm_bt<1,2><<<dim3(16,32), 256, 0, stream>>>(AO, Wot, (void*)out, bo, 1024, 1024);
}

// Round 12
// 190.409 us; speedup vs baseline: 1.0916x; 1.0014x over previous
//
#include <hip/hip_runtime.h>

#define D_MODEL 1024
#define SEQ     2048
#define BATCH   2
#define NHEAD   16
#define HDIM    64

typedef __attribute__((ext_vector_type(4))) float  f32x4;
typedef __attribute__((ext_vector_type(8))) __bf16 bf16x8;
typedef __attribute__((ext_vector_type(4))) __bf16 bf16x4;
typedef __attribute__((ext_vector_type(2))) unsigned int u32x2;

__device__ __forceinline__ void gld_lds16(const void* g, void* l) {
  __builtin_amdgcn_global_load_lds(
      (const __attribute__((address_space(1))) void*)g,
      (__attribute__((address_space(3))) void*)l, 16, 0, 0);
}

// ---------------- convert x (fp32 -> bf16), vectorized ----------------
__global__ void k_convert(const float* __restrict__ in, __bf16* __restrict__ out) {
  int i = blockIdx.x * blockDim.x + threadIdx.x;   // one float4 per thread
  float4 v = ((const float4*)in)[i];
  bf16x4 o;
  o[0] = (__bf16)v.x; o[1] = (__bf16)v.y; o[2] = (__bf16)v.z; o[3] = (__bf16)v.w;
  ((bf16x4*)out)[i] = o;
}

// ------------- transpose + convert weights: W[k][n] -> Wt[n][k] bf16 -------------
// Wq is additionally scaled by 1/sqrt(D_MODEL) = 1/32 (exact in bf16).
__global__ void k_transw(const float* __restrict__ Wq, const float* __restrict__ Wk,
                         const float* __restrict__ Wv, const float* __restrict__ Wo,
                         __bf16* __restrict__ Wqkvt, __bf16* __restrict__ Wot) {
  __shared__ __bf16 T[64][72];
  const int z = blockIdx.z;
  const float* src = (z==0)?Wq:(z==1)?Wk:(z==2)?Wv:Wo;
  __bf16* dst = (z<3) ? (Wqkvt + (size_t)z*D_MODEL*D_MODEL) : Wot;
  const float scl = (z==0) ? 0.03125f : 1.0f;      // fold softmax scale into Wq
  const int k0 = blockIdx.x*64, n0 = blockIdx.y*64;
  const int t = threadIdx.x;
  const int kl = t>>4, nl4 = (t&15)*4;
  #pragma unroll
  for (int part = 0; part < 4; ++part) {
    const int k = part*16 + kl;
    float4 v = *(const float4*)(src + (size_t)(k0+k)*D_MODEL + n0 + nl4);
    T[nl4+0][k] = (__bf16)(v.x*scl);
    T[nl4+1][k] = (__bf16)(v.y*scl);
    T[nl4+2][k] = (__bf16)(v.z*scl);
    T[nl4+3][k] = (__bf16)(v.w*scl);
  }
  __syncthreads();
  const int nl = t>>3, kc = (t&7)*8;
  #pragma unroll
  for (int part = 0; part < 2; ++part) {
    int n = part*32 + nl;
    bf16x8 o = *(const bf16x8*)&T[n][kc];
    *(bf16x8*)(dst + (size_t)(n0+n)*D_MODEL + k0 + kc) = o;
  }
}

// ------------- bf16 MFMA GEMM, 128 x (32*NI) tile, BK=32, Bt is [N][K] -------------
// NI = B-fragments per wave (4 -> BN=128, 2 -> BN=64).
template<int OUTF32, int NI>
__global__ __launch_bounds__(256)
void k_gemm_bt(const __bf16* __restrict__ A, const __bf16* __restrict__ Bt,
               void* __restrict__ Cv, const float* __restrict__ bias,
               const int K, const int N) {
  __shared__ __bf16 As[128*32];
  __shared__ __bf16 Bs[NI*32*32];        // BN = NI*32 rows x 32 k
  const int t = threadIdx.x;
  const int w = t>>6, l = t&63;
  const int lr = l&15, g = l>>4;
  const int BN = NI*32;
  const int m0 = blockIdx.y*128, n0 = blockIdx.x*BN;
  const int wr = (w>>1)*64, wc = (w&1)*(16*NI);
  f32x4 acc[4][NI] = {};

  const int srow = w*16 + (l>>2);
  const int sc8  = (l&3)*8;
  const __bf16* Ag = A  + (size_t)(m0 + srow)*K + sc8;
  const __bf16* Bg = Bt + (size_t)(n0 + srow)*K + sc8;
  char* Al = (char*)As + w*1024;
  char* Bl = (char*)Bs + w*1024;

  for (int k0 = 0; k0 < K; k0 += 32) {
    __syncthreads();
    gld_lds16(Ag + k0,                 Al);
    gld_lds16(Ag + (size_t)64*K + k0,  Al + 4096);
    gld_lds16(Bg + k0,                 Bl);
    if (NI == 4)
      gld_lds16(Bg + (size_t)64*K + k0, Bl + 4096);
    __syncthreads();
    bf16x8 af[4], bf[NI];
    #pragma unroll
    for (int mi=0;mi<4;++mi)
      af[mi] = *(const bf16x8*)((const char*)As + (wr + mi*16 + lr)*64 + (g<<4));
    #pragma unroll
    for (int ni=0;ni<NI;++ni)
      bf[ni] = *(const bf16x8*)((const char*)Bs + (wc + ni*16 + lr)*64 + (g<<4));
    #pragma unroll
    for (int mi=0;mi<4;++mi)
      #pragma unroll
      for (int ni=0;ni<NI;++ni)
        acc[mi][ni] = __builtin_amdgcn_mfma_f32_16x16x32_bf16(af[mi], bf[ni], acc[mi][ni], 0, 0, 0);
  }

  if (OUTF32) {
    float* C = (float*)Cv;
    #pragma unroll
    for (int ni=0;ni<NI;++ni) {
      const int col = n0 + wc + ni*16 + lr;
      const float bv = bias[col];
      #pragma unroll
      for (int mi=0;mi<4;++mi)
        #pragma unroll
        for (int r=0;r<4;++r) {
          const int row = m0 + wr + mi*16 + g*4 + r;
          C[(size_t)row*N + col] = acc[mi][ni][r] + bv;
        }
    }
  } else {
    __bf16* C = (__bf16*)Cv;
    #pragma unroll
    for (int ni=0;ni<NI;++ni) {
      const int col = n0 + wc + ni*16 + lr;
      #pragma unroll
      for (int mi=0;mi<4;++mi)
        #pragma unroll
        for (int r=0;r<4;++r) {
          const int row = m0 + wr + mi*16 + g*4 + r;
          C[(size_t)row*N + col] = (__bf16)acc[mi][ni][r];
        }
    }
  }
}

// ------------- causal flash attention, swapped-QK^T structure -------------
// One q-tile (64 rows) per block; grid = 1024 (4 blocks/CU: ids {c,c+256,...}).
// MAKESPAN FIX v2 (R11 counters): old map gave CU c the qb set
// {cc, 31-cc, cc, 31-cc} -> the TWO 32-iter blocks shared one CU and
// contended (measured: 32 x ~1.5us = 50us). New map offsets sweeps 2,3 by
// +16: per-CU qb = {cc, 31-cc, (cc+16)%32, 31-((cc+16)%32)} -> sum still 66
// (uniform), but no CU hosts two heavy blocks (e.g. cc=0 -> {0,31,16,15}).
// bh = xcd + 8s unchanged: K/V of each head stays on one XCD's L2
// (measured: FETCH 119MB -> 12MB).
__global__ __launch_bounds__(256)
void k_attn(const __bf16* __restrict__ QKV, __bf16* __restrict__ AO) {
  __shared__ __bf16 Ks[2][64*64];   // [key][dh] rows 128B, chunk ^= (key&7)
  __shared__ __bf16 Vs[2][64*64];   // subtiled [kb][nb][16][16] row-major, 512B each
  const int t = threadIdx.x;
  const int w = t>>6, l = t&63;
  const int lr = l&15, g = l>>4;

  const int id = blockIdx.x;
  const int xcd = id & 7, j = id >> 3;
  const int s = j >> 5, cc = j & 31;
  const int ccx = (s & 2) ? ((cc + 16) & 31) : cc;   // spread heavy blocks
  const int qb = (s & 1) ? (31 - ccx) : ccx;
  const int bh = xcd + 8*s;                  // all 32 q-blocks of bh on XCD xcd
  const int b = bh >> 4, h = bh & 15;
  const size_t rb = (size_t)b*SEQ;
  const int nt = qb + 1;
  const int q0 = qb*64 + w*16;

  // staging: thread -> (key row skey / skey+32, dh chunk sc*8)
  const int skey = t>>3, sc = t&7;
  const __bf16* Kg = QKV + rb*3072 + 1024 + h*64 + sc*8;
  const __bf16* Vg = Kg + 1024;
  const int ksw = skey*128 + ((sc ^ (skey&7))<<4);                        // K write byte off
  const int vsw = ((skey>>4)*4 + (sc>>1))*512 + (skey&15)*32 + (sc&1)*16; // V write byte off

  // Q fragments (B-operand: col q = q0+lr, k-slice dh = kc*32+g*8)
  bf16x8 qf[2];
  #pragma unroll
  for (int kc=0;kc<2;++kc)
    qf[kc] = *(const bf16x8*)(QKV + (rb + q0 + lr)*3072 + h*64 + kc*32 + g*8);

  f32x4 oacc[4] = {};
  float mrun = -1e30f, lrun = 0.f;

  // prologue: tile 0 -> regs -> LDS buf0; then prefetch tile 1 -> regs
  uint4 kR0 = *(const uint4*)(Kg + (size_t)skey*3072);
  uint4 kR1 = *(const uint4*)(Kg + (size_t)(skey+32)*3072);
  uint4 vR0 = *(const uint4*)(Vg + (size_t)skey*3072);
  uint4 vR1 = *(const uint4*)(Vg + (size_t)(skey+32)*3072);
  {
    char* K0 = (char*)&Ks[0][0]; char* V0 = (char*)&Vs[0][0];
    *(uint4*)(K0 + ksw) = kR0;  *(uint4*)(K0 + ksw + 4096) = kR1;
    *(uint4*)(V0 + vsw) = vR0;  *(uint4*)(V0 + vsw + 4096) = vR1;
  }
  if (nt > 1) {
    kR0 = *(const uint4*)(Kg + (size_t)(64+skey)*3072);
    kR1 = *(const uint4*)(Kg + (size_t)(64+skey+32)*3072);
    vR0 = *(const uint4*)(Vg + (size_t)(64+skey)*3072);
    vR1 = *(const uint4*)(Vg + (size_t)(64+skey+32)*3072);
  }

  int cur = 0;
  for (int kt = 0; kt < nt; ++kt) {
    __syncthreads();                     // buf[cur] fully written; prev reads done
    if (kt+1 < nt) {                     // stage next tile into other buffer
      char* Kn = (char*)&Ks[cur^1][0]; char* Vn = (char*)&Vs[cur^1][0];
      *(uint4*)(Kn + ksw) = kR0;  *(uint4*)(Kn + ksw + 4096) = kR1;
      *(uint4*)(Vn + vsw) = vR0;  *(uint4*)(Vn + vsw + 4096) = vR1;
      if (kt+2 < nt) {                   // issue loads for tile kt+2 (hide under compute)
        const size_t base = (size_t)(kt+2)*64;
        kR0 = *(const uint4*)(Kg + (base+skey)*3072);
        kR1 = *(const uint4*)(Kg + (base+skey+32)*3072);
        vR0 = *(const uint4*)(Vg + (base+skey)*3072);
        vR1 = *(const uint4*)(Vg + (base+skey+32)*3072);
      }
    }

    // ---- QK^T (swapped: A=K rows, B=Q cols) ----
    const char* Kb = (const char*)&Ks[cur][0];
    f32x4 sa[4] = {};
    #pragma unroll
    for (int kc=0;kc<2;++kc)
      #pragma unroll
      for (int kb=0;kb<4;++kb) {
        bf16x8 kfv = *(const bf16x8*)(Kb + (kb*16+lr)*128 + (((kc*4+g) ^ (lr&7))<<4));
        sa[kb] = __builtin_amdgcn_mfma_f32_16x16x32_bf16(kfv, qf[kc], sa[kb], 0,0,0);
      }

    if (kt == nt-1) {                    // diagonal tile: causal mask
      const int qg = q0 + lr;
      #pragma unroll
      for (int kb=0;kb<4;++kb)
        #pragma unroll
        for (int r=0;r<4;++r)
          if (kt*64 + kb*16 + 4*g + r > qg) sa[kb][r] = -1e30f;
    }

    // ---- online softmax (lane-local row q=q0+lr; reduce over 4 g-lanes) ----
    // Tree reductions (R12): depth ~4 vs 15-deep serial chain on the
    // latency-critical path (T_eff ~758ns/iter was the measured limiter).
    float mk[4];
    #pragma unroll
    for (int kb=0;kb<4;++kb)
      mk[kb] = fmaxf(fmaxf(sa[kb][0], sa[kb][1]), fmaxf(sa[kb][2], sa[kb][3]));
    float mx = fmaxf(fmaxf(mk[0], mk[1]), fmaxf(mk[2], mk[3]));
    mx = fmaxf(mx, __shfl_xor(mx, 16));
    mx = fmaxf(mx, __shfl_xor(mx, 32));
    if (!__all(mx <= mrun + 8.0f)) {     // defer-max: rescale only on real growth
      const float mnew = fmaxf(mrun, mx);
      const float al = __expf(mrun - mnew);
      lrun *= al;
      float alq[4];
      #pragma unroll
      for (int r=0;r<4;++r) alq[r] = __shfl(al, g*4+r);
      #pragma unroll
      for (int nb=0;nb<4;++nb)
        #pragma unroll
        for (int r=0;r<4;++r) oacc[nb][r] *= alq[r];
      mrun = mnew;
    }
    float ps[4];
    #pragma unroll
    for (int kb=0;kb<4;++kb) {
      #pragma unroll
      for (int r=0;r<4;++r) { float p = __expf(sa[kb][r]-mrun); sa[kb][r] = p; }
      ps[kb] = (sa[kb][0]+sa[kb][1]) + (sa[kb][2]+sa[kb][3]);
    }
    float ls = (ps[0]+ps[1]) + (ps[2]+ps[3]);
    ls += __shfl_xor(ls, 16);
    ls += __shfl_xor(ls, 32);
    lrun += ls;

    // ---- PV: pa lane-local pack; V via hw transpose read ----
    // Key-permutation note (verified R5): pa slot (g, j / 4+j) holds keys
    // 32kc+4g+j / 32kc+16+4g+j; tr_read of subtiles [2kc][nb],[2kc+1][nb]
    // delivers V for the SAME per-slot keys -> contraction exact.
    const __attribute__((address_space(3))) char* trp =
        (const __attribute__((address_space(3))) char*)((const char*)&Vs[cur][0]) + l*8;
    #pragma unroll
    for (int kc=0;kc<2;++kc) {
      bf16x8 pa;
      #pragma unroll
      for (int j2=0;j2<4;++j2) { pa[j2] = (__bf16)sa[2*kc][j2]; pa[4+j2] = (__bf16)sa[2*kc+1][j2]; }
      u32x2 t0[4], t1[4];
      #pragma unroll
      for (int nb=0;nb<4;++nb) {
        asm volatile("ds_read_b64_tr_b16 %0, %1 offset:%2"
                     : "=v"(t0[nb]) : "v"(trp), "i"(((2*kc)*4+nb)*512) : "memory");
        asm volatile("ds_read_b64_tr_b16 %0, %1 offset:%2"
                     : "=v"(t1[nb]) : "v"(trp), "i"(((2*kc+1)*4+nb)*512) : "memory");
      }
      asm volatile("s_waitcnt lgkmcnt(0)" ::: "memory");
      __builtin_amdgcn_sched_barrier(0);   // rule 18: don't hoist MFMA above the wait
      #pragma unroll
      for (int nb=0;nb<4;++nb) {
        union { u32x2 h[2]; bf16x8 v; } U;
        U.h[0] = t0[nb]; U.h[1] = t1[nb];
        oacc[nb] = __builtin_amdgcn_mfma_f32_16x16x32_bf16(pa, U.v, oacc[nb], 0,0,0);
      }
    }
    cur ^= 1;
  }

  // ---- epilogue: divide by l, write AO ----
  const float rinv = 1.0f / lrun;
  float rq[4];
  #pragma unroll
  for (int r=0;r<4;++r) rq[r] = __shfl(rinv, g*4+r);
  #pragma unroll
  for (int nb=0;nb<4;++nb)
    #pragma unroll
    for (int r=0;r<4;++r)
      AO[(rb + q0 + g*4 + r)*1024 + h*64 + nb*16 + lr] = (__bf16)(oacc[nb][r] * rq[r]);
}

extern "C" void kernel_launch(void* const* d_in, const int* in_sizes, int n_in,
                              void* d_out, int out_size, void* d_ws, size_t ws_size,
                              hipStream_t stream) {
  (void)in_sizes; (void)n_in; (void)out_size; (void)ws_size;
  const float* x  = (const float*)d_in[0];
  const float* Wq = (const float*)d_in[1];
  const float* Wk = (const float*)d_in[2];
  const float* Wv = (const float*)d_in[3];
  const float* Wo = (const float*)d_in[4];
  const float* bo = (const float*)d_in[5];
  float* out = (float*)d_out;
  char* ws = (char*)d_ws;

  __bf16* Xbf   = (__bf16*)(ws);                      // [0,8M)   x bf16; reused as AO
  __bf16* Wqkvt = (__bf16*)(ws + (size_t)(8<<20));    // [8M,14M) Wq|Wk|Wv ^T [3072][1024]
  __bf16* Wot   = (__bf16*)(ws + (size_t)(14<<20));   // [14M,16M) Wo ^T [1024][1024]
  __bf16* QKV   = (__bf16*)(ws + (size_t)(16<<20));   // [16M,40M) [4096][3072]
  __bf16* AO    = Xbf;

  k_convert<<<4096, 256, 0, stream>>>(x, Xbf);
  k_transw<<<dim3(16,16,4), 256, 0, stream>>>(Wq, Wk, Wv, Wo, Wqkvt, Wot);
  k_gemm_bt<0,4><<<dim3(24,32), 256, 0, stream>>>(Xbf, Wqkvt, (void*)QKV, nullptr, 1024, 3072);
  k_attn<<<1024, 256, 0, stream>>>(QKV, AO);
  k_gemm_bt<1,2><<<dim3(16,32), 256, 0, stream>>>(AO, Wot, (void*)out, bo, 1024, 1024);
}